// Round 11
// baseline (280.869 us; speedup 1.0000x reference)
//
#include <hip/hip_runtime.h>

#define TPB 256
#define HOR 28
#define LOG2E 1.44269504088896340736f

typedef _Float16 f16;
typedef __attribute__((ext_vector_type(2))) _Float16 f16x2;
typedef __attribute__((ext_vector_type(4))) _Float16 f16x4;
typedef __attribute__((ext_vector_type(8))) _Float16 f16x8;
typedef __attribute__((ext_vector_type(4))) float f32x4;

union V8 { f16x8 v8; f16x4 v4[2]; f16x2 h2[4]; };

#define MFMA16(A,B,C) __builtin_amdgcn_mfma_f32_16x16x32_f16((A),(B),(C),0,0,0)

__device__ __forceinline__ f16x2 pk2(float a, float b) {
    return __builtin_bit_cast(f16x2, __builtin_amdgcn_cvt_pkrtz(a, b));
}
__device__ __forceinline__ float sigm_pos(float lg) {   // sigmoid(lg), lg in natural units
    return __builtin_amdgcn_rcpf(1.0f + __builtin_amdgcn_exp2f(-LOG2E * lg));
}

// W stride: 68 f16 = 34 dwords; row*68+4g ≡ 0 mod 4 -> every ds_read_b64 aligned.
#define WS 68

__global__ __launch_bounds__(TPB, 3) void predictor_kernel(
    const float* __restrict__ features,
    const float* __restrict__ last_value,
    const float* __restrict__ W_ih,
    const float* __restrict__ W_hh,
    const float* __restrict__ b_ih,
    const float* __restrict__ b_hh,
    const float* __restrict__ Wp,
    const float* __restrict__ bp,
    const float* __restrict__ Wo1,
    const float* __restrict__ bo1,
    const float* __restrict__ Wo2,
    const float* __restrict__ bo2,
    const float* __restrict__ Wg1,
    const float* __restrict__ bg1,
    const float* __restrict__ Wg2,
    const float* __restrict__ bg2,
    const float* __restrict__ log_decay,
    float* __restrict__ out)
{
    // f16 union region: 16000 elems = 32000 B:
    //  phase1: s_wp[64*136]=8704 | s_wg1[32*136]=4352 | s_wg2[32*40]=1280  (14336)
    //  main  : s_whh[192*68]=13056 | s_wo1[32*68]=2176 | s_wx[192*4]=768   (16000)
    __shared__ __align__(16) f16 s_mem[16000];

    const int tid = threadIdx.x;
    const int wv = tid >> 6, ln = tid & 63;
    const int a = ln & 15, g = ln >> 4;
    const int row0 = blockIdx.x * 128 + wv * 32;    // 32 rows per wave (2 streams)

    const f32x4 ZF = {0.f, 0.f, 0.f, 0.f};
    const f16x2 Z2 = {(f16)0.f, (f16)0.f};
    const f16x4 ZH4 = {(f16)0.f, (f16)0.f, (f16)0.f, (f16)0.f};

    f16* s_wp  = s_mem;            // phase 1
    f16* s_wg1 = s_mem + 8704;
    f16* s_wg2 = s_mem + 13056;

    // ---- stage phase-1 weights (f16) ----
    for (int i = tid; i < 64 * 128; i += TPB) s_wp [(i >> 7) * 136 + (i & 127)] = (f16)Wp[i];
    for (int i = tid; i < 32 * 128; i += TPB) s_wg1[(i >> 7) * 136 + (i & 127)] = (f16)Wg1[i];
    for (int i = tid; i < 32 * 32; i += TPB) {
        int t = i >> 5, s = i & 31;
        int q = ((s >> 2) & 1) * 16 + ((s >> 3) & 3) * 4 + (s & 3);   // sigma''
        s_wg2[t * 40 + s] = (f16)((t < HOR) ? Wg2[t * 32 + q] : 0.0f);
    }

    // ---- shared per-lane constants (unit u = 16c + 4g + r) ----
    f16x2 bH[4][2];
    #pragma unroll
    for (int c = 0; c < 4; ++c)
        #pragma unroll
        for (int p = 0; p < 2; ++p) {
            int u0 = c * 16 + g * 4 + 2 * p;
            bH[c][p] = pk2(b_hh[128 + u0] * 2.0f * LOG2E, b_hh[128 + u0 + 1] * 2.0f * LOG2E);
        }
    f16x2 bo1q[2][2], wo2q[2][2];
    #pragma unroll
    for (int mt = 0; mt < 2; ++mt)
        #pragma unroll
        for (int p = 0; p < 2; ++p) {
            int q0 = mt * 16 + g * 4 + 2 * p;
            bo1q[mt][p] = pk2(bo1[q0], bo1[q0 + 1]);
            wo2q[mt][p] = pk2(Wo2[q0], Wo2[q0 + 1]);
        }
    const float bo2v = bo2[0];
    const float edc  = LOG2E * __builtin_amdgcn_exp2f(LOG2E * log_decay[0]);
    const float lvA  = last_value[row0 + a];
    const float lvB  = last_value[row0 + 16 + a];
    const bool  g0   = (g == 0);

    __syncthreads();

    f32x4 h4A[4], h4B[4];
    float ga0, ga1, ga2, ga3, ga4, ga5, ga6, ga7;   // stream A gates
    float gb0, gb1, gb2, gb3, gb4, gb5, gb6, gb7;   // stream B gates

// ---- phase 1 per stream: h0 + refine gate ----
#define PHASE1(H4, G0_, G1_, G2_, G3_, G4_, G5_, G6_, G7_, ROFF) do { \
    V8 FF0, FF1, FF2, FF3; \
    { \
        const float* fb_ = features + (size_t)(row0 + (ROFF) + a) * 128 + g * 8; \
        f32x4 v0, v1; \
        v0 = *(const f32x4*)(fb_);       v1 = *(const f32x4*)(fb_ + 4); \
        FF0.h2[0]=pk2(v0[0],v0[1]); FF0.h2[1]=pk2(v0[2],v0[3]); FF0.h2[2]=pk2(v1[0],v1[1]); FF0.h2[3]=pk2(v1[2],v1[3]); \
        v0 = *(const f32x4*)(fb_ + 32);  v1 = *(const f32x4*)(fb_ + 36); \
        FF1.h2[0]=pk2(v0[0],v0[1]); FF1.h2[1]=pk2(v0[2],v0[3]); FF1.h2[2]=pk2(v1[0],v1[1]); FF1.h2[3]=pk2(v1[2],v1[3]); \
        v0 = *(const f32x4*)(fb_ + 64);  v1 = *(const f32x4*)(fb_ + 68); \
        FF2.h2[0]=pk2(v0[0],v0[1]); FF2.h2[1]=pk2(v0[2],v0[3]); FF2.h2[2]=pk2(v1[0],v1[1]); FF2.h2[3]=pk2(v1[2],v1[3]); \
        v0 = *(const f32x4*)(fb_ + 96);  v1 = *(const f32x4*)(fb_ + 100); \
        FF3.h2[0]=pk2(v0[0],v0[1]); FF3.h2[1]=pk2(v0[2],v0[3]); FF3.h2[2]=pk2(v1[0],v1[1]); FF3.h2[3]=pk2(v1[2],v1[3]); \
    } \
    _Pragma("unroll") \
    for (int nt = 0; nt < 4; ++nt) { \
        f32x4 acc = ZF; \
        const f16* wp_ = &s_wp[(nt * 16 + a) * 136 + g * 8]; \
        acc = MFMA16(*(const f16x8*)(wp_),       FF0.v8, acc); \
        acc = MFMA16(*(const f16x8*)(wp_ + 32),  FF1.v8, acc); \
        acc = MFMA16(*(const f16x8*)(wp_ + 64),  FF2.v8, acc); \
        acc = MFMA16(*(const f16x8*)(wp_ + 96),  FF3.v8, acc); \
        _Pragma("unroll") \
        for (int r = 0; r < 4; ++r) acc[r] += bp[nt * 16 + g * 4 + r]; \
        H4[nt] = acc; \
    } \
    f32x4 a1_0, a1_1; \
    { \
        f32x4 acc = ZF; \
        const f16* wg_ = &s_wg1[a * 136 + g * 8]; \
        acc = MFMA16(*(const f16x8*)(wg_),       FF0.v8, acc); \
        acc = MFMA16(*(const f16x8*)(wg_ + 32),  FF1.v8, acc); \
        acc = MFMA16(*(const f16x8*)(wg_ + 64),  FF2.v8, acc); \
        acc = MFMA16(*(const f16x8*)(wg_ + 96),  FF3.v8, acc); \
        _Pragma("unroll") \
        for (int r = 0; r < 4; ++r) acc[r] = fmaxf(acc[r] + bg1[g * 4 + r], 0.f); \
        a1_0 = acc; \
    } \
    { \
        f32x4 acc = ZF; \
        const f16* wg_ = &s_wg1[(16 + a) * 136 + g * 8]; \
        acc = MFMA16(*(const f16x8*)(wg_),       FF0.v8, acc); \
        acc = MFMA16(*(const f16x8*)(wg_ + 32),  FF1.v8, acc); \
        acc = MFMA16(*(const f16x8*)(wg_ + 64),  FF2.v8, acc); \
        acc = MFMA16(*(const f16x8*)(wg_ + 96),  FF3.v8, acc); \
        _Pragma("unroll") \
        for (int r = 0; r < 4; ++r) acc[r] = fmaxf(acc[r] + bg1[16 + g * 4 + r], 0.f); \
        a1_1 = acc; \
    } \
    V8 A1_; \
    A1_.h2[0] = pk2(a1_0[0], a1_0[1]); A1_.h2[1] = pk2(a1_0[2], a1_0[3]); \
    A1_.h2[2] = pk2(a1_1[0], a1_1[1]); A1_.h2[3] = pk2(a1_1[2], a1_1[3]); \
    { \
        f32x4 ac0 = ZF, ac1 = ZF; \
        ac0 = MFMA16(*(const f16x8*)&s_wg2[a * 40 + g * 8],        A1_.v8, ac0); \
        ac1 = MFMA16(*(const f16x8*)&s_wg2[(16 + a) * 40 + g * 8], A1_.v8, ac1); \
        G0_ = sigm_pos(ac0[0] + bg2[g * 4 + 0]); \
        G1_ = sigm_pos(ac0[1] + bg2[g * 4 + 1]); \
        G2_ = sigm_pos(ac0[2] + bg2[g * 4 + 2]); \
        G3_ = sigm_pos(ac0[3] + bg2[g * 4 + 3]); \
        int t4_ = 16 + g * 4; \
        G4_ = sigm_pos(ac1[0] + ((t4_ + 0 < HOR) ? bg2[t4_ + 0] : 0.f)); \
        G5_ = sigm_pos(ac1[1] + ((t4_ + 1 < HOR) ? bg2[t4_ + 1] : 0.f)); \
        G6_ = sigm_pos(ac1[2] + ((t4_ + 2 < HOR) ? bg2[t4_ + 2] : 0.f)); \
        G7_ = sigm_pos(ac1[3] + ((t4_ + 3 < HOR) ? bg2[t4_ + 3] : 0.f)); \
    } } while (0)

    PHASE1(h4A, ga0, ga1, ga2, ga3, ga4, ga5, ga6, ga7, 0);
    PHASE1(h4B, gb0, gb1, gb2, gb3, gb4, gb5, gb6, gb7, 16);
#undef PHASE1

    // ---- restage: main-loop weights ----
    __syncthreads();
    f16* s_whh = s_mem;              // [192][68]; rows 0..63 r, 64..127 z, 128..191 n
    f16* s_wo1 = s_mem + 13056;      // [32][68]
    f16* s_wx  = s_mem + 15232;      // [192][4]: {Wih*s, bias*s, 0, 0}
    for (int i = tid; i < 192 * WS; i += TPB) {
        int rr = i / WS, cc = i - rr * WS;
        float s = (rr < 128) ? -LOG2E : 2.0f * LOG2E;
        s_whh[i] = (f16)((cc < 64) ? W_hh[rr * 64 + cc] * s : 0.0f);
    }
    for (int i = tid; i < 32 * WS; i += TPB) {
        int rr = i / WS, cc = i - rr * WS;
        s_wo1[i] = (f16)((cc < 64) ? Wo1[rr * 64 + cc] : 0.0f);
    }
    for (int i = tid; i < 192; i += TPB) {
        float s = (i < 128) ? -LOG2E : 2.0f * LOG2E;
        s_wx[i * 4 + 0] = (f16)(W_ih[i] * s);
        s_wx[i * 4 + 1] = (f16)(((i < 128) ? (b_ih[i] + b_hh[i]) : b_ih[i]) * s);
        s_wx[i * 4 + 2] = (f16)0.f;
        s_wx[i * 4 + 3] = (f16)0.f;
    }
    __syncthreads();

    const int wr = a * WS + 4 * g;

    // ---- pack initial fragments ----
    V8 F0A, F1A, F0B, F1B, F2A, F2B;
#define PACKF(F0_, F1_, H4) do { \
    F0_.h2[0] = pk2(H4[0][0], H4[0][1]); F0_.h2[1] = pk2(H4[0][2], H4[0][3]); \
    F0_.h2[2] = pk2(H4[1][0], H4[1][1]); F0_.h2[3] = pk2(H4[1][2], H4[1][3]); \
    F1_.h2[0] = pk2(H4[2][0], H4[2][1]); F1_.h2[1] = pk2(H4[2][2], H4[2][3]); \
    F1_.h2[2] = pk2(H4[3][0], H4[3][1]); F1_.h2[3] = pk2(H4[3][2], H4[3][3]); } while (0)
    PACKF(F0A, F1A, h4A);
    PACKF(F0B, F1B, h4B);
    F2A.h2[0] = Z2; F2A.h2[1] = Z2; F2A.h2[2] = Z2; F2A.h2[3] = Z2;
    F2B.h2[0] = Z2; F2B.h2[1] = Z2; F2B.h2[2] = Z2; F2B.h2[3] = Z2;

    float xA = lvA, xB = lvB;

// shared-W dual-stream gate MMAs
#define GATE3_2(ACCA, ACCB, BR, c) do { \
        V8 w0_, w1_, w2_; \
        const int rb_ = (BR + (c) * 16) * WS + wr; \
        w0_.v4[0] = *(const f16x4*)&s_whh[rb_]; \
        w0_.v4[1] = *(const f16x4*)&s_whh[rb_ + 16]; \
        w1_.v4[0] = *(const f16x4*)&s_whh[rb_ + 32]; \
        w1_.v4[1] = *(const f16x4*)&s_whh[rb_ + 48]; \
        w2_.v4[0] = *(const f16x4*)&s_wx[(BR + (c) * 16 + a) * 4]; \
        w2_.v4[1] = ZH4; \
        ACCA = MFMA16(w0_.v8, F0A.v8, ZF); \
        ACCB = MFMA16(w0_.v8, F0B.v8, ZF); \
        ACCA = MFMA16(w1_.v8, F1A.v8, ACCA); \
        ACCB = MFMA16(w1_.v8, F1B.v8, ACCB); \
        ACCA = MFMA16(w2_.v8, F2A.v8, ACCA); \
        ACCB = MFMA16(w2_.v8, F2B.v8, ACCB); } while (0)

#define GATEN_2(ACCA, ACC2A, ACCB, ACC2B, c) do { \
        V8 w0_, w1_, w2_; \
        const int rb_ = (128 + (c) * 16) * WS + wr; \
        w0_.v4[0] = *(const f16x4*)&s_whh[rb_]; \
        w0_.v4[1] = *(const f16x4*)&s_whh[rb_ + 16]; \
        w1_.v4[0] = *(const f16x4*)&s_whh[rb_ + 32]; \
        w1_.v4[1] = *(const f16x4*)&s_whh[rb_ + 48]; \
        w2_.v4[0] = *(const f16x4*)&s_wx[(128 + (c) * 16 + a) * 4]; \
        w2_.v4[1] = ZH4; \
        ACCA = MFMA16(w0_.v8, F0A.v8, ZF); \
        ACCB = MFMA16(w0_.v8, F0B.v8, ZF); \
        ACCA = MFMA16(w1_.v8, F1A.v8, ACCA); \
        ACCB = MFMA16(w1_.v8, F1B.v8, ACCB); \
        ACC2A = MFMA16(w2_.v8, F2A.v8, ZF); \
        ACC2B = MFMA16(w2_.v8, F2B.v8, ZF); } while (0)

#define GRU_CELL(H4, c, AR, AZ, AN, AN2) do { \
        _Pragma("unroll") \
        for (int p = 0; p < 2; ++p) { \
            _Pragma("unroll") \
            for (int q = 0; q < 2; ++q) { \
                int r = p * 2 + q; \
                float rg = __builtin_amdgcn_rcpf(1.0f + __builtin_amdgcn_exp2f(AR[r])); \
                float pb = 1.0f + __builtin_amdgcn_exp2f(AZ[r]); \
                float ghn = AN[r] + (float)bH[c][p][q]; \
                float E  = __builtin_amdgcn_exp2f(fmaf(rg, ghn, AN2[r])); \
                float pE = 1.0f + E; \
                float rD = __builtin_amdgcn_rcpf(pb * pE); \
                float zg = rD * pE; \
                float ivE = rD * pb; \
                float nc = fmaf(-2.0f, ivE, 1.0f); \
                float hv = H4[c][r]; \
                H4[c][r] = fmaf(zg, hv - nc, nc); \
            } \
        } } while (0)

    #pragma unroll 1
    for (int t = 0; t < HOR; ++t) {
        asm volatile("" ::: "memory");
        F2A.h2[0] = g0 ? pk2(xA, 1.0f) : Z2;
        F2B.h2[0] = g0 ? pk2(xB, 1.0f) : Z2;

        #pragma unroll
        for (int c = 0; c < 4; ++c) {
            f32x4 aRA, aZA, aNA, aN2A, aRB, aZB, aNB, aN2B;
            GATE3_2(aRA, aRB, 0, c);
            GATE3_2(aZA, aZB, 64, c);
            GATEN_2(aNA, aN2A, aNB, aN2B, c);
            GRU_CELL(h4A, c, aRA, aZA, aNA, aN2A);
            GRU_CELL(h4B, c, aRB, aZB, aNB, aN2B);
        }

        PACKF(F0A, F1A, h4A);
        PACKF(F0B, F1B, h4B);

        // head (shared Wo1 reads)
        V8 wo;
        f32x4 o0A = ZF, o1A = ZF, o0B = ZF, o1B = ZF;
        wo.v4[0] = *(const f16x4*)&s_wo1[wr];
        wo.v4[1] = *(const f16x4*)&s_wo1[wr + 16];
        o0A = MFMA16(wo.v8, F0A.v8, o0A); o0B = MFMA16(wo.v8, F0B.v8, o0B);
        wo.v4[0] = *(const f16x4*)&s_wo1[wr + 32];
        wo.v4[1] = *(const f16x4*)&s_wo1[wr + 48];
        o0A = MFMA16(wo.v8, F1A.v8, o0A); o0B = MFMA16(wo.v8, F1B.v8, o0B);
        wo.v4[0] = *(const f16x4*)&s_wo1[16 * WS + wr];
        wo.v4[1] = *(const f16x4*)&s_wo1[16 * WS + wr + 16];
        o1A = MFMA16(wo.v8, F0A.v8, o1A); o1B = MFMA16(wo.v8, F0B.v8, o1B);
        wo.v4[0] = *(const f16x4*)&s_wo1[16 * WS + wr + 32];
        wo.v4[1] = *(const f16x4*)&s_wo1[16 * WS + wr + 48];
        o1A = MFMA16(wo.v8, F1A.v8, o1A); o1B = MFMA16(wo.v8, F1B.v8, o1B);

        float partA = 0.f, partB = 0.f;
        #pragma unroll
        for (int p = 0; p < 2; ++p)
            #pragma unroll
            for (int q = 0; q < 2; ++q) {
                int r = 2 * p + q;
                partA += fmaxf(o0A[r] + (float)bo1q[0][p][q], 0.f) * (float)wo2q[0][p][q];
                partA += fmaxf(o1A[r] + (float)bo1q[1][p][q], 0.f) * (float)wo2q[1][p][q];
                partB += fmaxf(o0B[r] + (float)bo1q[0][p][q], 0.f) * (float)wo2q[0][p][q];
                partB += fmaxf(o1B[r] + (float)bo1q[1][p][q], 0.f) * (float)wo2q[1][p][q];
            }
        partA += __shfl_xor(partA, 16);
        partA += __shfl_xor(partA, 32);
        partB += __shfl_xor(partB, 16);
        partB += __shfl_xor(partB, 32);
        float predA = partA + bo2v;
        float predB = partB + bo2v;

        if (g == ((t >> 2) & 3)) {
            float dc = __builtin_amdgcn_exp2f(-edc * (float)(t + 1));
            float s01, s23, gvf;
            s01 = (t & 1) ? ((t & 16) ? ga5 : ga1) : ((t & 16) ? ga4 : ga0);
            s23 = (t & 1) ? ((t & 16) ? ga7 : ga3) : ((t & 16) ? ga6 : ga2);
            gvf = (t & 2) ? s23 : s01;
            float lvdcA = lvA * dc;
            out[(size_t)(row0 + a) * HOR + t] = fmaf(gvf, predA - lvdcA, lvdcA);
            s01 = (t & 1) ? ((t & 16) ? gb5 : gb1) : ((t & 16) ? gb4 : gb0);
            s23 = (t & 1) ? ((t & 16) ? gb7 : gb3) : ((t & 16) ? gb6 : gb2);
            gvf = (t & 2) ? s23 : s01;
            float lvdcB = lvB * dc;
            out[(size_t)(row0 + 16 + a) * HOR + t] = fmaf(gvf, predB - lvdcB, lvdcB);
        }
        xA = predA;
        xB = predB;
    }
#undef GATE3_2
#undef GATEN_2
#undef GRU_CELL
#undef PACKF
}

extern "C" void kernel_launch(void* const* d_in, const int* in_sizes, int n_in,
                              void* d_out, int out_size, void* d_ws, size_t ws_size,
                              hipStream_t stream) {
    const float* features   = (const float*)d_in[0];
    const float* last_value = (const float*)d_in[1];
    const float* W_ih       = (const float*)d_in[2];
    const float* W_hh       = (const float*)d_in[3];
    const float* b_ih       = (const float*)d_in[4];
    const float* b_hh       = (const float*)d_in[5];
    const float* Wp         = (const float*)d_in[6];
    const float* bp         = (const float*)d_in[7];
    const float* Wo1        = (const float*)d_in[8];
    const float* bo1        = (const float*)d_in[9];
    const float* Wo2        = (const float*)d_in[10];
    const float* bo2        = (const float*)d_in[11];
    const float* Wg1        = (const float*)d_in[12];
    const float* bg1        = (const float*)d_in[13];
    const float* Wg2        = (const float*)d_in[14];
    const float* bg2        = (const float*)d_in[15];
    const float* log_decay  = (const float*)d_in[16];
    float* out = (float*)d_out;

    dim3 grid(131072 / 128), block(TPB);
    predictor_kernel<<<grid, block, 0, stream>>>(
        features, last_value, W_ih, W_hh, b_ih, b_hh, Wp, bp,
        Wo1, bo1, Wo2, bo2, Wg1, bg1, Wg2, bg2, log_decay, out);
}

// Round 12
// 252.188 us; speedup vs baseline: 1.1137x; 1.1137x over previous
//
#include <hip/hip_runtime.h>

#define TPB 256
#define HOR 28
#define LOG2E 1.44269504088896340736f

typedef _Float16 f16;
typedef __attribute__((ext_vector_type(2))) _Float16 f16x2;
typedef __attribute__((ext_vector_type(4))) _Float16 f16x4;
typedef __attribute__((ext_vector_type(8))) _Float16 f16x8;
typedef __attribute__((ext_vector_type(4))) float f32x4;

union V8 { f16x8 v8; f16x4 v4[2]; f16x2 h2[4]; };

#define MFMA16(A,B,C) __builtin_amdgcn_mfma_f32_16x16x32_f16((A),(B),(C),0,0,0)

__device__ __forceinline__ f16x2 pk2(float a, float b) {
    return __builtin_bit_cast(f16x2, __builtin_amdgcn_cvt_pkrtz(a, b));
}
__device__ __forceinline__ float sigm_pos(float lg) {   // sigmoid(lg), lg in natural units
    return __builtin_amdgcn_rcpf(1.0f + __builtin_amdgcn_exp2f(-LOG2E * lg));
}

// W stride: 68 f16 = 34 dwords; row*68+4g ≡ 0 mod 4 -> every ds_read_b64 aligned.
#define WS 68

__global__ __launch_bounds__(TPB, 2) void predictor_kernel(
    const float* __restrict__ features,
    const float* __restrict__ last_value,
    const float* __restrict__ W_ih,
    const float* __restrict__ W_hh,
    const float* __restrict__ b_ih,
    const float* __restrict__ b_hh,
    const float* __restrict__ Wp,
    const float* __restrict__ bp,
    const float* __restrict__ Wo1,
    const float* __restrict__ bo1,
    const float* __restrict__ Wo2,
    const float* __restrict__ bo2,
    const float* __restrict__ Wg1,
    const float* __restrict__ bg1,
    const float* __restrict__ Wg2,
    const float* __restrict__ bg2,
    const float* __restrict__ log_decay,
    float* __restrict__ out)
{
    // f16 union region: 16000 elems = 32000 B:
    //  phase1: s_wp[64*136]=8704 | s_wg1[32*136]=4352 | s_wg2[32*40]=1280  (14336)
    //  main  : s_whh[192*68]=13056 | s_wo1[32*68]=2176 | s_wx[192*4]=768   (16000)
    __shared__ __align__(16) f16 s_mem[16000];

    const int tid = threadIdx.x;
    const int wv = tid >> 6, ln = tid & 63;
    const int a = ln & 15, g = ln >> 4;
    const int row0 = blockIdx.x * 128 + wv * 32;    // 32 rows per wave (2 streams)

    const f32x4 ZF = {0.f, 0.f, 0.f, 0.f};
    const f16x2 Z2 = {(f16)0.f, (f16)0.f};
    const f16x4 ZH4 = {(f16)0.f, (f16)0.f, (f16)0.f, (f16)0.f};

    f16* s_wp  = s_mem;            // phase 1
    f16* s_wg1 = s_mem + 8704;
    f16* s_wg2 = s_mem + 13056;

    // ---- stage phase-1 weights (f16) ----
    for (int i = tid; i < 64 * 128; i += TPB) s_wp [(i >> 7) * 136 + (i & 127)] = (f16)Wp[i];
    for (int i = tid; i < 32 * 128; i += TPB) s_wg1[(i >> 7) * 136 + (i & 127)] = (f16)Wg1[i];
    for (int i = tid; i < 32 * 32; i += TPB) {
        int t = i >> 5, s = i & 31;
        int q = ((s >> 2) & 1) * 16 + ((s >> 3) & 3) * 4 + (s & 3);   // sigma''
        s_wg2[t * 40 + s] = (f16)((t < HOR) ? Wg2[t * 32 + q] : 0.0f);
    }

    // ---- shared per-lane constants (unit u = 16c + 4g + r) ----
    f16x2 bH[4][2];
    #pragma unroll
    for (int c = 0; c < 4; ++c)
        #pragma unroll
        for (int p = 0; p < 2; ++p) {
            int u0 = c * 16 + g * 4 + 2 * p;
            bH[c][p] = pk2(b_hh[128 + u0] * 2.0f * LOG2E, b_hh[128 + u0 + 1] * 2.0f * LOG2E);
        }
    f16x2 bo1q[2][2], wo2q[2][2];
    #pragma unroll
    for (int mt = 0; mt < 2; ++mt)
        #pragma unroll
        for (int p = 0; p < 2; ++p) {
            int q0 = mt * 16 + g * 4 + 2 * p;
            bo1q[mt][p] = pk2(bo1[q0], bo1[q0 + 1]);
            wo2q[mt][p] = pk2(Wo2[q0], Wo2[q0 + 1]);
        }
    const float bo2v = bo2[0];
    const float edc  = LOG2E * __builtin_amdgcn_exp2f(LOG2E * log_decay[0]);
    const float lvA  = last_value[row0 + a];
    const float lvB  = last_value[row0 + 16 + a];
    const bool  g0   = (g == 0);

    __syncthreads();

    f32x4 h4A[4], h4B[4];
    float ga0, ga1, ga2, ga3, ga4, ga5, ga6, ga7;   // stream A gates
    float gb0, gb1, gb2, gb3, gb4, gb5, gb6, gb7;   // stream B gates

// ---- phase 1 per stream: h0 + refine gate ----
#define PHASE1(H4, G0_, G1_, G2_, G3_, G4_, G5_, G6_, G7_, ROFF) do { \
    V8 FF0, FF1, FF2, FF3; \
    { \
        const float* fb_ = features + (size_t)(row0 + (ROFF) + a) * 128 + g * 8; \
        f32x4 v0, v1; \
        v0 = *(const f32x4*)(fb_);       v1 = *(const f32x4*)(fb_ + 4); \
        FF0.h2[0]=pk2(v0[0],v0[1]); FF0.h2[1]=pk2(v0[2],v0[3]); FF0.h2[2]=pk2(v1[0],v1[1]); FF0.h2[3]=pk2(v1[2],v1[3]); \
        v0 = *(const f32x4*)(fb_ + 32);  v1 = *(const f32x4*)(fb_ + 36); \
        FF1.h2[0]=pk2(v0[0],v0[1]); FF1.h2[1]=pk2(v0[2],v0[3]); FF1.h2[2]=pk2(v1[0],v1[1]); FF1.h2[3]=pk2(v1[2],v1[3]); \
        v0 = *(const f32x4*)(fb_ + 64);  v1 = *(const f32x4*)(fb_ + 68); \
        FF2.h2[0]=pk2(v0[0],v0[1]); FF2.h2[1]=pk2(v0[2],v0[3]); FF2.h2[2]=pk2(v1[0],v1[1]); FF2.h2[3]=pk2(v1[2],v1[3]); \
        v0 = *(const f32x4*)(fb_ + 96);  v1 = *(const f32x4*)(fb_ + 100); \
        FF3.h2[0]=pk2(v0[0],v0[1]); FF3.h2[1]=pk2(v0[2],v0[3]); FF3.h2[2]=pk2(v1[0],v1[1]); FF3.h2[3]=pk2(v1[2],v1[3]); \
    } \
    _Pragma("unroll") \
    for (int nt = 0; nt < 4; ++nt) { \
        f32x4 acc = ZF; \
        const f16* wp_ = &s_wp[(nt * 16 + a) * 136 + g * 8]; \
        acc = MFMA16(*(const f16x8*)(wp_),       FF0.v8, acc); \
        acc = MFMA16(*(const f16x8*)(wp_ + 32),  FF1.v8, acc); \
        acc = MFMA16(*(const f16x8*)(wp_ + 64),  FF2.v8, acc); \
        acc = MFMA16(*(const f16x8*)(wp_ + 96),  FF3.v8, acc); \
        _Pragma("unroll") \
        for (int r = 0; r < 4; ++r) acc[r] += bp[nt * 16 + g * 4 + r]; \
        H4[nt] = acc; \
    } \
    f32x4 a1_0, a1_1; \
    { \
        f32x4 acc = ZF; \
        const f16* wg_ = &s_wg1[a * 136 + g * 8]; \
        acc = MFMA16(*(const f16x8*)(wg_),       FF0.v8, acc); \
        acc = MFMA16(*(const f16x8*)(wg_ + 32),  FF1.v8, acc); \
        acc = MFMA16(*(const f16x8*)(wg_ + 64),  FF2.v8, acc); \
        acc = MFMA16(*(const f16x8*)(wg_ + 96),  FF3.v8, acc); \
        _Pragma("unroll") \
        for (int r = 0; r < 4; ++r) acc[r] = fmaxf(acc[r] + bg1[g * 4 + r], 0.f); \
        a1_0 = acc; \
    } \
    { \
        f32x4 acc = ZF; \
        const f16* wg_ = &s_wg1[(16 + a) * 136 + g * 8]; \
        acc = MFMA16(*(const f16x8*)(wg_),       FF0.v8, acc); \
        acc = MFMA16(*(const f16x8*)(wg_ + 32),  FF1.v8, acc); \
        acc = MFMA16(*(const f16x8*)(wg_ + 64),  FF2.v8, acc); \
        acc = MFMA16(*(const f16x8*)(wg_ + 96),  FF3.v8, acc); \
        _Pragma("unroll") \
        for (int r = 0; r < 4; ++r) acc[r] = fmaxf(acc[r] + bg1[16 + g * 4 + r], 0.f); \
        a1_1 = acc; \
    } \
    V8 A1_; \
    A1_.h2[0] = pk2(a1_0[0], a1_0[1]); A1_.h2[1] = pk2(a1_0[2], a1_0[3]); \
    A1_.h2[2] = pk2(a1_1[0], a1_1[1]); A1_.h2[3] = pk2(a1_1[2], a1_1[3]); \
    { \
        f32x4 ac0 = ZF, ac1 = ZF; \
        ac0 = MFMA16(*(const f16x8*)&s_wg2[a * 40 + g * 8],        A1_.v8, ac0); \
        ac1 = MFMA16(*(const f16x8*)&s_wg2[(16 + a) * 40 + g * 8], A1_.v8, ac1); \
        G0_ = sigm_pos(ac0[0] + bg2[g * 4 + 0]); \
        G1_ = sigm_pos(ac0[1] + bg2[g * 4 + 1]); \
        G2_ = sigm_pos(ac0[2] + bg2[g * 4 + 2]); \
        G3_ = sigm_pos(ac0[3] + bg2[g * 4 + 3]); \
        int t4_ = 16 + g * 4; \
        G4_ = sigm_pos(ac1[0] + ((t4_ + 0 < HOR) ? bg2[t4_ + 0] : 0.f)); \
        G5_ = sigm_pos(ac1[1] + ((t4_ + 1 < HOR) ? bg2[t4_ + 1] : 0.f)); \
        G6_ = sigm_pos(ac1[2] + ((t4_ + 2 < HOR) ? bg2[t4_ + 2] : 0.f)); \
        G7_ = sigm_pos(ac1[3] + ((t4_ + 3 < HOR) ? bg2[t4_ + 3] : 0.f)); \
    } } while (0)

    PHASE1(h4A, ga0, ga1, ga2, ga3, ga4, ga5, ga6, ga7, 0);
    PHASE1(h4B, gb0, gb1, gb2, gb3, gb4, gb5, gb6, gb7, 16);
#undef PHASE1

    // ---- restage: main-loop weights ----
    __syncthreads();
    f16* s_whh = s_mem;              // [192][68]; rows 0..63 r, 64..127 z, 128..191 n
    f16* s_wo1 = s_mem + 13056;      // [32][68]
    f16* s_wx  = s_mem + 15232;      // [192][4]: {Wih*s, bias*s, 0, 0}
    for (int i = tid; i < 192 * WS; i += TPB) {
        int rr = i / WS, cc = i - rr * WS;
        float s = (rr < 128) ? -LOG2E : 2.0f * LOG2E;
        s_whh[i] = (f16)((cc < 64) ? W_hh[rr * 64 + cc] * s : 0.0f);
    }
    for (int i = tid; i < 32 * WS; i += TPB) {
        int rr = i / WS, cc = i - rr * WS;
        s_wo1[i] = (f16)((cc < 64) ? Wo1[rr * 64 + cc] : 0.0f);
    }
    for (int i = tid; i < 192; i += TPB) {
        float s = (i < 128) ? -LOG2E : 2.0f * LOG2E;
        s_wx[i * 4 + 0] = (f16)(W_ih[i] * s);
        s_wx[i * 4 + 1] = (f16)(((i < 128) ? (b_ih[i] + b_hh[i]) : b_ih[i]) * s);
        s_wx[i * 4 + 2] = (f16)0.f;
        s_wx[i * 4 + 3] = (f16)0.f;
    }
    __syncthreads();

    const int wr = a * WS + 4 * g;

    // ---- pack initial fragments ----
    V8 F0A, F1A, F0B, F1B, F2A, F2B;
#define PACKF(F0_, F1_, H4) do { \
    F0_.h2[0] = pk2(H4[0][0], H4[0][1]); F0_.h2[1] = pk2(H4[0][2], H4[0][3]); \
    F0_.h2[2] = pk2(H4[1][0], H4[1][1]); F0_.h2[3] = pk2(H4[1][2], H4[1][3]); \
    F1_.h2[0] = pk2(H4[2][0], H4[2][1]); F1_.h2[1] = pk2(H4[2][2], H4[2][3]); \
    F1_.h2[2] = pk2(H4[3][0], H4[3][1]); F1_.h2[3] = pk2(H4[3][2], H4[3][3]); } while (0)
    PACKF(F0A, F1A, h4A);
    PACKF(F0B, F1B, h4B);
    F2A.h2[0] = Z2; F2A.h2[1] = Z2; F2A.h2[2] = Z2; F2A.h2[3] = Z2;
    F2B.h2[0] = Z2; F2B.h2[1] = Z2; F2B.h2[2] = Z2; F2B.h2[3] = Z2;

    float xA = lvA, xB = lvB;

// shared-W dual-stream gate MMAs
#define GATE3_2(ACCA, ACCB, BR, c) do { \
        V8 w0_, w1_, w2_; \
        const int rb_ = (BR + (c) * 16) * WS + wr; \
        w0_.v4[0] = *(const f16x4*)&s_whh[rb_]; \
        w0_.v4[1] = *(const f16x4*)&s_whh[rb_ + 16]; \
        w1_.v4[0] = *(const f16x4*)&s_whh[rb_ + 32]; \
        w1_.v4[1] = *(const f16x4*)&s_whh[rb_ + 48]; \
        w2_.v4[0] = *(const f16x4*)&s_wx[(BR + (c) * 16 + a) * 4]; \
        w2_.v4[1] = ZH4; \
        ACCA = MFMA16(w0_.v8, F0A.v8, ZF); \
        ACCB = MFMA16(w0_.v8, F0B.v8, ZF); \
        ACCA = MFMA16(w1_.v8, F1A.v8, ACCA); \
        ACCB = MFMA16(w1_.v8, F1B.v8, ACCB); \
        ACCA = MFMA16(w2_.v8, F2A.v8, ACCA); \
        ACCB = MFMA16(w2_.v8, F2B.v8, ACCB); } while (0)

#define GATEN_2(ACCA, ACC2A, ACCB, ACC2B, c) do { \
        V8 w0_, w1_, w2_; \
        const int rb_ = (128 + (c) * 16) * WS + wr; \
        w0_.v4[0] = *(const f16x4*)&s_whh[rb_]; \
        w0_.v4[1] = *(const f16x4*)&s_whh[rb_ + 16]; \
        w1_.v4[0] = *(const f16x4*)&s_whh[rb_ + 32]; \
        w1_.v4[1] = *(const f16x4*)&s_whh[rb_ + 48]; \
        w2_.v4[0] = *(const f16x4*)&s_wx[(128 + (c) * 16 + a) * 4]; \
        w2_.v4[1] = ZH4; \
        ACCA = MFMA16(w0_.v8, F0A.v8, ZF); \
        ACCB = MFMA16(w0_.v8, F0B.v8, ZF); \
        ACCA = MFMA16(w1_.v8, F1A.v8, ACCA); \
        ACCB = MFMA16(w1_.v8, F1B.v8, ACCB); \
        ACC2A = MFMA16(w2_.v8, F2A.v8, ZF); \
        ACC2B = MFMA16(w2_.v8, F2B.v8, ZF); } while (0)

#define GRU_CELL(H4, c, AR, AZ, AN, AN2) do { \
        _Pragma("unroll") \
        for (int p = 0; p < 2; ++p) { \
            _Pragma("unroll") \
            for (int q = 0; q < 2; ++q) { \
                int r = p * 2 + q; \
                float rg = __builtin_amdgcn_rcpf(1.0f + __builtin_amdgcn_exp2f(AR[r])); \
                float pb = 1.0f + __builtin_amdgcn_exp2f(AZ[r]); \
                float ghn = AN[r] + (float)bH[c][p][q]; \
                float E  = __builtin_amdgcn_exp2f(fmaf(rg, ghn, AN2[r])); \
                float pE = 1.0f + E; \
                float rD = __builtin_amdgcn_rcpf(pb * pE); \
                float zg = rD * pE; \
                float ivE = rD * pb; \
                float nc = fmaf(-2.0f, ivE, 1.0f); \
                float hv = H4[c][r]; \
                H4[c][r] = fmaf(zg, hv - nc, nc); \
            } \
        } } while (0)

    #pragma unroll 1
    for (int t = 0; t < HOR; ++t) {
        asm volatile("" ::: "memory");
        F2A.h2[0] = g0 ? pk2(xA, 1.0f) : Z2;
        F2B.h2[0] = g0 ? pk2(xB, 1.0f) : Z2;

        #pragma unroll
        for (int c = 0; c < 4; ++c) {
            f32x4 aRA, aZA, aNA, aN2A, aRB, aZB, aNB, aN2B;
            GATE3_2(aRA, aRB, 0, c);
            GATE3_2(aZA, aZB, 64, c);
            GATEN_2(aNA, aN2A, aNB, aN2B, c);
            GRU_CELL(h4A, c, aRA, aZA, aNA, aN2A);
            GRU_CELL(h4B, c, aRB, aZB, aNB, aN2B);
        }

        PACKF(F0A, F1A, h4A);
        PACKF(F0B, F1B, h4B);

        // head (shared Wo1 reads)
        V8 wo;
        f32x4 o0A = ZF, o1A = ZF, o0B = ZF, o1B = ZF;
        wo.v4[0] = *(const f16x4*)&s_wo1[wr];
        wo.v4[1] = *(const f16x4*)&s_wo1[wr + 16];
        o0A = MFMA16(wo.v8, F0A.v8, o0A); o0B = MFMA16(wo.v8, F0B.v8, o0B);
        wo.v4[0] = *(const f16x4*)&s_wo1[wr + 32];
        wo.v4[1] = *(const f16x4*)&s_wo1[wr + 48];
        o0A = MFMA16(wo.v8, F1A.v8, o0A); o0B = MFMA16(wo.v8, F1B.v8, o0B);
        wo.v4[0] = *(const f16x4*)&s_wo1[16 * WS + wr];
        wo.v4[1] = *(const f16x4*)&s_wo1[16 * WS + wr + 16];
        o1A = MFMA16(wo.v8, F0A.v8, o1A); o1B = MFMA16(wo.v8, F0B.v8, o1B);
        wo.v4[0] = *(const f16x4*)&s_wo1[16 * WS + wr + 32];
        wo.v4[1] = *(const f16x4*)&s_wo1[16 * WS + wr + 48];
        o1A = MFMA16(wo.v8, F1A.v8, o1A); o1B = MFMA16(wo.v8, F1B.v8, o1B);

        float partA = 0.f, partB = 0.f;
        #pragma unroll
        for (int p = 0; p < 2; ++p)
            #pragma unroll
            for (int q = 0; q < 2; ++q) {
                int r = 2 * p + q;
                partA += fmaxf(o0A[r] + (float)bo1q[0][p][q], 0.f) * (float)wo2q[0][p][q];
                partA += fmaxf(o1A[r] + (float)bo1q[1][p][q], 0.f) * (float)wo2q[1][p][q];
                partB += fmaxf(o0B[r] + (float)bo1q[0][p][q], 0.f) * (float)wo2q[0][p][q];
                partB += fmaxf(o1B[r] + (float)bo1q[1][p][q], 0.f) * (float)wo2q[1][p][q];
            }
        partA += __shfl_xor(partA, 16);
        partA += __shfl_xor(partA, 32);
        partB += __shfl_xor(partB, 16);
        partB += __shfl_xor(partB, 32);
        float predA = partA + bo2v;
        float predB = partB + bo2v;

        if (g == ((t >> 2) & 3)) {
            float dc = __builtin_amdgcn_exp2f(-edc * (float)(t + 1));
            float s01, s23, gvf;
            s01 = (t & 1) ? ((t & 16) ? ga5 : ga1) : ((t & 16) ? ga4 : ga0);
            s23 = (t & 1) ? ((t & 16) ? ga7 : ga3) : ((t & 16) ? ga6 : ga2);
            gvf = (t & 2) ? s23 : s01;
            float lvdcA = lvA * dc;
            out[(size_t)(row0 + a) * HOR + t] = fmaf(gvf, predA - lvdcA, lvdcA);
            s01 = (t & 1) ? ((t & 16) ? gb5 : gb1) : ((t & 16) ? gb4 : gb0);
            s23 = (t & 1) ? ((t & 16) ? gb7 : gb3) : ((t & 16) ? gb6 : gb2);
            gvf = (t & 2) ? s23 : s01;
            float lvdcB = lvB * dc;
            out[(size_t)(row0 + 16 + a) * HOR + t] = fmaf(gvf, predB - lvdcB, lvdcB);
        }
        xA = predA;
        xB = predB;
    }
#undef GATE3_2
#undef GATEN_2
#undef GRU_CELL
#undef PACKF
}

extern "C" void kernel_launch(void* const* d_in, const int* in_sizes, int n_in,
                              void* d_out, int out_size, void* d_ws, size_t ws_size,
                              hipStream_t stream) {
    const float* features   = (const float*)d_in[0];
    const float* last_value = (const float*)d_in[1];
    const float* W_ih       = (const float*)d_in[2];
    const float* W_hh       = (const float*)d_in[3];
    const float* b_ih       = (const float*)d_in[4];
    const float* b_hh       = (const float*)d_in[5];
    const float* Wp         = (const float*)d_in[6];
    const float* bp         = (const float*)d_in[7];
    const float* Wo1        = (const float*)d_in[8];
    const float* bo1        = (const float*)d_in[9];
    const float* Wo2        = (const float*)d_in[10];
    const float* bo2        = (const float*)d_in[11];
    const float* Wg1        = (const float*)d_in[12];
    const float* bg1        = (const float*)d_in[13];
    const float* Wg2        = (const float*)d_in[14];
    const float* bg2        = (const float*)d_in[15];
    const float* log_decay  = (const float*)d_in[16];
    float* out = (float*)d_out;

    dim3 grid(131072 / 128), block(TPB);
    predictor_kernel<<<grid, block, 0, stream>>>(
        features, last_value, W_ih, W_hh, b_ih, b_hh, Wp, bp,
        Wo1, bo1, Wo2, bo2, Wg1, bg1, Wg2, bg2, log_decay, out);
}